// Round 18
// baseline (348.500 us; speedup 1.0000x reference)
//
#include <hip/hip_runtime.h>
#include <hip/hip_bf16.h>

typedef __attribute__((ext_vector_type(8))) short  short8;
typedef __attribute__((ext_vector_type(4))) float  f32x4;

#define MFMA16(A,B,C) __builtin_amdgcn_mfma_f32_16x16x32_bf16((A),(B),(C),0,0,0)

// LDS-visibility barrier WITHOUT the vmcnt drain (used only at B, where no
// vmem-produced data is consumed before the next A's vmcnt(0)).
__device__ __forceinline__ void barrier_nv() {
    __builtin_amdgcn_sched_barrier(0);
    asm volatile("s_waitcnt lgkmcnt(0)" ::: "memory");
    __builtin_amdgcn_s_barrier();
    __builtin_amdgcn_sched_barrier(0);
}
#define VM_WAIT0() do { asm volatile("s_waitcnt vmcnt(0)" ::: "memory"); \
                        __builtin_amdgcn_sched_barrier(0); } while (0)

// ---- fp32 -> bf16 hi/lo split (weights only keep the lo part) ----
__device__ __forceinline__ void split2(float x0, float x1, unsigned &hp, unsigned &lp) {
    __hip_bfloat162 h = __float22bfloat162_rn(float2{x0, x1});
    union { __hip_bfloat162 b; unsigned u; } uh, ul;
    uh.b = h;
    float f0 = __bfloat162float(h.x);
    float f1 = __bfloat162float(h.y);
    ul.b = __float22bfloat162_rn(float2{x0 - f0, x1 - f1});
    hp = uh.u; lp = ul.u;
}
// hi-only pack: 2 floats -> packed bf16x2 dword
__device__ __forceinline__ unsigned pack2(float x0, float x1) {
    union { __hip_bfloat162 b; unsigned u; } v;
    v.b = __float22bfloat162_rn(float2{x0, x1});
    return v.u;
}
// hi-only pack: 8 floats -> short8 fragment (4 cvt_pk)
__device__ __forceinline__ short8 pack8(const f32x4 a, const f32x4 b) {
    union { short8 s; unsigned u[4]; } H;
    H.u[0] = pack2(a[0], a[1]);
    H.u[1] = pack2(a[2], a[3]);
    H.u[2] = pack2(b[0], b[1]);
    H.u[3] = pack2(b[2], b[3]);
    return H.s;
}

// XOR-swizzled byte offset inside a [16 rows][64 bf16] plane (row stride 128B).
__device__ __forceinline__ unsigned swz(unsigned row, unsigned colbyte) {
    return row * 128u + (colbyte ^ ((row & 7u) << 4));
}

// async global->LDS, 16B/lane (per-lane global addr, lane-linear LDS dest).
__device__ __forceinline__ void gld16(const void* g, void* l) {
    __builtin_amdgcn_global_load_lds(
        (const __attribute__((address_space(1))) unsigned int*)g,
        (__attribute__((address_space(3))) unsigned int*)l, 16, 0, 0);
}

// Tree level, transposed-MFMA, pair-per-iteration (R17 numerics + T5 setprio):
// ALL activations hi-only bf16; weights hi+lo; every GEMM slot = 2 MFMAs.
// Sync: vmcnt(0) before barrier A each iteration (canonical gld16 pattern).
// R18: s_setprio(1) around the phase-2 h-GEMM MFMA clusters (T5) — the
// phase-split schedule gives waves distinct roles, so priority arbitration
// can favor MFMA-entering waves.
template<bool LEAF, bool FINAL>
__global__ __launch_bounds__(256, 3)
void grnn_mfma(const float* __restrict__ cont,   // rows x 32 (fp32)
               const int*   __restrict__ child,  // rows x 2
               const void*  __restrict__ ein_,   // emb bf16 rows / contents8 fp32 rows (128B)
               const float* __restrict__ Wu,     // 32 x 64
               const float* __restrict__ bu,     // 64
               const float* __restrict__ Wh,     // 192 x 64
               const float* __restrict__ bh,     // 64
               void*        __restrict__ eout_,  // bf16 rows (fp32 if FINAL)
               int npairs)                        // ntiles/2
{
    constexpr int TS  = 4096;                 // staging bytes per tile (2 sides x 2KB)
    constexpr int STG = 2 * TS;               // per parity (one pair)
    constexpr int NPL = LEAF ? 3 : 1;         // u planes (hi only): [uL,uR,]u
    constexpr int UST = NPL * 2048;
    constexpr int FST = LEAF ? 3072 : 1024;   // frag planes per tile (hi-only, 1KB each)
    __shared__ __align__(16) char lds[2 * STG + 2 * UST + 2 * FST];
    char* ub  = lds + 2 * STG;
    char* fpl = ub + 2 * UST;

    const int lane = threadIdx.x & 63;
    const int w    = threadIdx.x >> 6;
    const int cidx = lane & 15;
    const int g    = lane >> 4;

    // ---- weight fragments (hi/lo), transposed orientation ----
    short8 WhH[6], WhL[6], WuH, WuL;
#pragma unroll
    for (int s = 0; s < 6; ++s) {
        union { short8 s8; unsigned u[4]; } H, L;
#pragma unroll
        for (int q = 0; q < 4; ++q) {
            const int k = 32 * s + 8 * g + 2 * q;
            split2(Wh[k * 64 + 16 * w + cidx], Wh[(k + 1) * 64 + 16 * w + cidx], H.u[q], L.u[q]);
        }
        WhH[s] = H.s8; WhL[s] = L.s8;
    }
    {
        union { short8 s8; unsigned u[4]; } H, L;
#pragma unroll
        for (int q = 0; q < 4; ++q) {
            const int k = 8 * g + 2 * q;
            split2(Wu[k * 64 + 16 * w + cidx], Wu[(k + 1) * 64 + 16 * w + cidx], H.u[q], L.u[q]);
        }
        WuH = H.s8; WuL = L.s8;
    }
    const f32x4 bu4 = *(const f32x4*)(bu + 16 * w + 4 * g);
    const f32x4 bh4 = *(const f32x4*)(bh + 16 * w + 4 * g);

    const char* eb = (const char*)ein_;
    const unsigned colb = 32u * w + 8u * g;
    const int S = gridDim.x;

    const int stile = w >> 1, sside = w & 1;   // staging share: (tile, side)
    const unsigned fo = (unsigned)g * 256u + (unsigned)cidx * 16u;  // 1KB plane slot
    const unsigned o0 = 512u * (g & 1) + 16u * cidx;                // fp32 x-frag
    const unsigned rg = (unsigned)(g >> 1) * 1024u;

    int p = blockIdx.x;
    const int p1 = (p + S < npairs) ? p + S : p;
    const int ps0 = LEAF ? ((p + 2 * S < npairs) ? p + 2 * S : p) : p1;

    int2 sA, sB;   // child rows of the pair staged at the next staging point

    // ---- prologue ----
    {
        const int2 cA = *(const int2*)(child + 2 * (2 * p * 16 + cidx));
        const int2 cB = *(const int2*)(child + 2 * ((2 * p + 1) * 16 + cidx));
        { int2 ch = stile ? cB : cA; const int c = sside ? ch.y : ch.x;
          char* d = lds + 0 * STG + stile * TS + sside * 2048;
          gld16(eb + (size_t)c * 128 +      g * 16, d);
          gld16(eb + (size_t)c * 128 + 64 + g * 16, d + 1024); }
        if (LEAF) {
            const int2 dA = *(const int2*)(child + 2 * (2 * p1 * 16 + cidx));
            const int2 dB = *(const int2*)(child + 2 * ((2 * p1 + 1) * 16 + cidx));
            int2 ch = stile ? dB : dA; const int c = sside ? ch.y : ch.x;
            char* d = lds + 1 * STG + stile * TS + sside * 2048;
            gld16(eb + (size_t)c * 128 +      g * 16, d);
            gld16(eb + (size_t)c * 128 + 64 + g * 16, d + 1024);
        }
        sA = *(const int2*)(child + 2 * (2 * ps0 * 16 + cidx));
        sB = *(const int2*)(child + 2 * ((2 * ps0 + 1) * 16 + cidx));
    }
    f32x4 c0, c1;
    if (w == 0) {
        const f32x4* pc = (const f32x4*)(cont + (size_t)(2 * p * 16 + cidx) * 32 + 8 * g);
        c0 = pc[0]; c1 = pc[1];
    } else if (w == (LEAF ? 2 : 1)) {
        const f32x4* pc = (const f32x4*)(cont + (size_t)((2 * p + 1) * 16 + cidx) * 32 + 8 * g);
        c0 = pc[0]; c1 = pc[1];
    }
    __syncthreads();   // full drain: prologue staging + regs complete

    // prologue frag jobs for pair p (hi-only packs)
    if (LEAF) {
        const int tt = w >> 1;
        if ((w & 1) == 0) {        // w0/w2: cont + xL of tile tt
            *(short8*)(fpl + tt * FST + fo) = pack8(c0, c1);
            const char* xb = lds + 0 * STG + tt * TS;
            const f32x4 a = *(const f32x4*)(xb + rg + o0);
            const f32x4 b = *(const f32x4*)(xb + rg + o0 + 256);
            *(short8*)(fpl + tt * FST + 1024 + fo) = pack8(a, b);
        } else {                    // w1/w3: xR of tile tt
            const char* xb = lds + 0 * STG + tt * TS + 2048;
            const f32x4 a = *(const f32x4*)(xb + rg + o0);
            const f32x4 b = *(const f32x4*)(xb + rg + o0 + 256);
            *(short8*)(fpl + tt * FST + 2048 + fo) = pack8(a, b);
        }
    } else if (w <= 1) {
        *(short8*)(fpl + w * FST + fo) = pack8(c0, c1);
    }
    __syncthreads();

    for (int k = 0; p < npairs; p += S, ++k) {
        const int pb = k & 1;
        const int pf = (p + S < npairs) ? p + S : p;
        const int pn = LEAF ? ((p + 3 * S < npairs) ? p + 3 * S : p)
                            : ((p + 2 * S < npairs) ? p + 2 * S : p);

        // ---- phase 1: u-GEMMs (2 MFMAs each) for both tiles; hi-only stash ----
#pragma unroll
        for (int tt = 0; tt < 2; ++tt) {
            const short8 aH = *(const short8*)(fpl + tt * FST + fo);
            f32x4 ua = bu4;
            ua = MFMA16(WuH, aH, ua);
            ua = MFMA16(WuL, aH, ua);
            const unsigned off = swz(cidx, colb);
            {
                unsigned h0 = pack2(fmaxf(ua[0], 0.f), fmaxf(ua[1], 0.f));
                unsigned h1 = pack2(fmaxf(ua[2], 0.f), fmaxf(ua[3], 0.f));
                *(uint2*)(ub + tt * UST + (NPL - 1) * 2048 + off) = uint2{h0, h1};
            }
            if (LEAF) {
#pragma unroll
                for (int sd = 0; sd < 2; ++sd) {
                    const short8 xH = *(const short8*)(fpl + tt * FST + (1 + sd) * 1024 + fo);
                    f32x4 ux = bu4;
                    ux = MFMA16(WuH, xH, ux);
                    ux = MFMA16(WuL, xH, ux);
                    unsigned h0 = pack2(fmaxf(ux[0], 0.f), fmaxf(ux[1], 0.f));
                    unsigned h1 = pack2(fmaxf(ux[2], 0.f), fmaxf(ux[3], 0.f));
                    *(uint2*)(ub + tt * UST + sd * 2048 + off) = uint2{h0, h1};
                }
            }
        }
        VM_WAIT0();      // ALL prior staging complete (canonical gld16 pattern)
        barrier_nv();    // A: staged buffers + u planes visible to all waves

        // ---- phase 2 ----
        if (w == 0) {
            const f32x4* pc = (const f32x4*)(cont + (size_t)(2 * pf * 16 + cidx) * 32 + 8 * g);
            c0 = pc[0]; c1 = pc[1];
        } else if (w == (LEAF ? 2 : 1)) {
            const f32x4* pc = (const f32x4*)(cont + (size_t)((2 * pf + 1) * 16 + cidx) * 32 + 8 * g);
            c0 = pc[0]; c1 = pc[1];
        }
        // stage next pair from pipelined child regs (128B-row form); drained
        // at the NEXT iteration's VM_WAIT0-before-A, consumed after that A.
        {
            int2 ch = stile ? sB : sA; const int c = sside ? ch.y : ch.x;
            char* d = lds + (LEAF ? pb : (pb ^ 1)) * STG + stile * TS + sside * 2048;
            gld16(eb + (size_t)c * 128 +      g * 16, d);
            gld16(eb + (size_t)c * 128 + 64 + g * 16, d + 1024);
        }
        __builtin_amdgcn_sched_barrier(0);
        int2 nA = *(const int2*)(child + 2 * (2 * pn * 16 + cidx));
        int2 nB = *(const int2*)(child + 2 * ((2 * pn + 1) * 16 + cidx));

        // h-GEMMs: every slot = 2 MFMAs (hi activation x hi/lo weight).
        // T5: boost priority through the MFMA cluster.
        f32x4 acc[2][2];
        acc[0][0] = bh4; acc[0][1] = f32x4{0.f, 0.f, 0.f, 0.f};
        acc[1][0] = bh4; acc[1][1] = f32x4{0.f, 0.f, 0.f, 0.f};
        __builtin_amdgcn_s_setprio(1);
        if (LEAF) {
#pragma unroll
            for (int tt = 0; tt < 2; ++tt)
#pragma unroll
            for (int q = 0; q < 3; ++q)
#pragma unroll
            for (int s = 0; s < 2; ++s) {
                const short8 aH = *(const short8*)(ub + tt * UST + q * 2048 + swz(cidx, 64 * s + 16 * g));
                const int Sl = 2 * q + s;
                acc[tt][s] = MFMA16(WhH[Sl], aH, acc[tt][s]);
                acc[tt][s] = MFMA16(WhL[Sl], aH, acc[tt][s]);
            }
        } else {
#pragma unroll
            for (int tt = 0; tt < 2; ++tt) {
                const char* hb = lds + pb * STG + tt * TS;
#pragma unroll
                for (int sd = 0; sd < 2; ++sd)
#pragma unroll
                for (int s = 0; s < 2; ++s) {
                    const short8 aH = *(const short8*)(hb + sd * 2048 + s * 1024 + 16 * lane);
                    const int Sl = 2 * sd + s;
                    acc[tt][sd] = MFMA16(WhH[Sl], aH, acc[tt][sd]);
                    acc[tt][sd] = MFMA16(WhL[Sl], aH, acc[tt][sd]);
                }
#pragma unroll
                for (int s = 0; s < 2; ++s) {
                    const short8 aH = *(const short8*)(ub + tt * UST + swz(cidx, 64 * s + 16 * g));
                    const int Sl = 4 + s;
                    acc[tt][s] = MFMA16(WhH[Sl], aH, acc[tt][s]);
                    acc[tt][s] = MFMA16(WhL[Sl], aH, acc[tt][s]);
                }
            }
        }
        __builtin_amdgcn_s_setprio(0);

        // frag jobs for pair pf (hi-only packs; staged x visible since last A)
        if (LEAF) {
            const char* xbase = lds + (pb ^ 1) * STG;
            const int tt = w >> 1;
            if ((w & 1) == 0) {        // w0/w2: cont + xL of tile tt
                *(short8*)(fpl + tt * FST + fo) = pack8(c0, c1);
                const char* xb = xbase + tt * TS;
                const f32x4 a = *(const f32x4*)(xb + rg + o0);
                const f32x4 b = *(const f32x4*)(xb + rg + o0 + 256);
                *(short8*)(fpl + tt * FST + 1024 + fo) = pack8(a, b);
            } else {                    // w1/w3: xR of tile tt
                const char* xb = xbase + tt * TS + 2048;
                const f32x4 a = *(const f32x4*)(xb + rg + o0);
                const f32x4 b = *(const f32x4*)(xb + rg + o0 + 256);
                *(short8*)(fpl + tt * FST + 2048 + fo) = pack8(a, b);
            }
        } else if (w <= 1) {
            *(short8*)(fpl + w * FST + fo) = pack8(c0, c1);
        }

        // ---- stores: tiles 2p, 2p+1 (bf16 128B rows; fp32 if FINAL) ----
#pragma unroll
        for (int tt = 0; tt < 2; ++tt) {
            const int T = 2 * p + tt;
            if (FINAL) {
                float* out = (float*)eout_;
                f32x4 v;
#pragma unroll
                for (int i = 0; i < 4; ++i) v[i] = fmaxf(acc[tt][0][i] + acc[tt][1][i], 0.f);
                *(f32x4*)(out + (size_t)(T * 16 + cidx) * 64 + 16 * w + 4 * g) = v;
            } else {
                char* out = (char*)eout_;
                const size_t rb = (size_t)(T * 16 + cidx) * 128;
                unsigned h0 = pack2(fmaxf(acc[tt][0][0] + acc[tt][1][0], 0.f),
                                    fmaxf(acc[tt][0][1] + acc[tt][1][1], 0.f));
                unsigned h1 = pack2(fmaxf(acc[tt][0][2] + acc[tt][1][2], 0.f),
                                    fmaxf(acc[tt][0][3] + acc[tt][1][3], 0.f));
                *(uint2*)(out + rb + colb) = uint2{h0, h1};
            }
        }
        barrier_nv();   // B: frag planes visible (ds ops only)
        sA = nA; sB = nB;
    }
}

extern "C" void kernel_launch(void* const* d_in, const int* in_sizes, int n_in,
                              void* d_out, int out_size, void* d_ws, size_t ws_size,
                              hipStream_t stream) {
    // inputs: contents0..8 = d_in[0..8], children0..7 = d_in[9..16],
    //         Wu = d_in[17], bu = d_in[18], Wh = d_in[19], bh = d_in[20]
    const float* Wu = (const float*)d_in[17];
    const float* bu = (const float*)d_in[18];
    const float* Wh = (const float*)d_in[19];
    const float* bh = (const float*)d_in[20];

    // emb_j stored as single-bf16 rows, 128B/row
    void* bufA = d_ws;                               // emb7/5/3/1
    void* bufB = (char*)d_ws + (size_t)268435456;    // emb6/4/2

    const void* ein = d_in[8];  // contents8 (fp32) for the fused leaf level
    for (int j = 7; j >= 0; --j) {
        const int n      = in_sizes[j] / 32;
        const int npairs = n / 32;
        void* eout = (j == 0) ? d_out : ((j & 1) ? bufA : bufB);
        int blocks = npairs < 4096 ? npairs : 4096;
        const float* cont  = (const float*)d_in[j];
        const int*   child = (const int*)d_in[9 + j];
        if (j == 7)
            grnn_mfma<true,  false><<<blocks, 256, 0, stream>>>(cont, child, ein, Wu, bu, Wh, bh, eout, npairs);
        else if (j == 0)
            grnn_mfma<false, true ><<<blocks, 256, 0, stream>>>(cont, child, ein, Wu, bu, Wh, bh, eout, npairs);
        else
            grnn_mfma<false, false><<<blocks, 256, 0, stream>>>(cont, child, ein, Wu, bu, Wh, bh, eout, npairs);
        ein = eout;
    }
}